// Round 1
// baseline (725.332 us; speedup 1.0000x reference)
//
#include <hip/hip_runtime.h>

// MQA forward, MI355X gfx950.
// B=4 H=32 S=2048 D=128, fp32 in/out, bf16 MFMA internally.
// Pre-pass 1: K fp32 -> bf16 (same layout) into d_ws.
// Pre-pass 2: V fp32 -> bf16 TRANSPOSED [B][D][S] into d_ws (PV needs key-contiguous B-frags).
// Main: flash attention, 4 waves/block, wave = 16 q-rows, KV tile = 64 keys,
//       K/V tiles in XOR-swizzled LDS, wave-parallel online softmax, P via LDS.

#define B_SZ 4
#define H_SZ 32
#define S_SZ 2048
#define D_SZ 128
#define QBLK 64
#define KBLK 64
#define SCALE_F 0.08838834764831845f
#define LOG2E 1.44269504088896340736f

typedef __attribute__((ext_vector_type(8))) __bf16 bf16x8;
typedef __attribute__((ext_vector_type(8))) unsigned short u16x8;
typedef __attribute__((ext_vector_type(4))) float f32x4;
typedef __attribute__((ext_vector_type(4))) unsigned int u32x4;

static __device__ __forceinline__ unsigned short f2bf(float f) {
    // RNE fp32 -> bf16 (inputs finite; no NaN handling needed)
    unsigned int u = __builtin_bit_cast(unsigned int, f);
    u += 0x7fffu + ((u >> 16) & 1u);
    return (unsigned short)(u >> 16);
}

__global__ void k_cvt_kernel(const float* __restrict__ src,
                             unsigned short* __restrict__ dst, int n4) {
    int i = blockIdx.x * blockDim.x + threadIdx.x;
    if (i >= n4) return;
    float4 v = reinterpret_cast<const float4*>(src)[i];
    ushort4 o;
    o.x = f2bf(v.x); o.y = f2bf(v.y); o.z = f2bf(v.z); o.w = f2bf(v.w);
    reinterpret_cast<ushort4*>(dst)[i] = o;
}

__global__ void v_tr_kernel(const float* __restrict__ V,
                            unsigned short* __restrict__ Vt) {
    // 64x64 tile transpose through LDS. grid (S/64, D/64, B), 256 thr.
    __shared__ unsigned short T[64][72];  // +8 pad
    const int k0 = blockIdx.x * 64;
    const int d0 = blockIdx.y * 64;
    const int b  = blockIdx.z;
    const int t  = threadIdx.x;
    const int r  = t >> 4;
    const int c4 = (t & 15) * 4;
#pragma unroll
    for (int rep = 0; rep < 4; ++rep) {
        int ki = rep * 16 + r;
        float4 v = *reinterpret_cast<const float4*>(
            &V[((size_t)(b * S_SZ + k0 + ki)) * D_SZ + d0 + c4]);
        T[ki][c4 + 0] = f2bf(v.x); T[ki][c4 + 1] = f2bf(v.y);
        T[ki][c4 + 2] = f2bf(v.z); T[ki][c4 + 3] = f2bf(v.w);
    }
    __syncthreads();
#pragma unroll
    for (int rep = 0; rep < 4; ++rep) {
        int di = rep * 16 + r;
        ushort4 o;
        o.x = T[c4 + 0][di]; o.y = T[c4 + 1][di];
        o.z = T[c4 + 2][di]; o.w = T[c4 + 3][di];
        *reinterpret_cast<ushort4*>(
            &Vt[((size_t)(b * D_SZ + d0 + di)) * S_SZ + k0 + c4]) = o;
    }
}

__global__ __launch_bounds__(256) void mqa_fwd_kernel(
        const float* __restrict__ Q,
        const unsigned short* __restrict__ Kb,   // [B][S][D] bf16
        const unsigned short* __restrict__ Vt,   // [B][D][S] bf16
        float* __restrict__ Out)
{
    // Swizzle everywhere: byte ^= (row&7)<<4 keeps 16B alignment, kills the
    // 16-way bank conflict of row-major D=128/64 tiles on ds_read_b128.
    __shared__ __align__(16) unsigned short Kl[64 * 128];   // [key][d]
    __shared__ __align__(16) unsigned short Vl[128 * 64];   // [d][key]
    __shared__ __align__(16) unsigned short Pl[4][16 * 64]; // per-wave [q][key]

    const int tid  = threadIdx.x;
    const int lane = tid & 63;
    const int w    = tid >> 6;
    const int l15  = lane & 15;
    const int lg   = lane >> 4;

    const int qt = blockIdx.x;
    const int h  = blockIdx.y;
    const int b  = blockIdx.z;

    // ---- Q fragments (A-frag: row=l15, k = lg*8+i per 32-wide chunk), pre-scaled ----
    const size_t qoff = (((size_t)b * H_SZ + h) * S_SZ + qt * QBLK + w * 16 + l15) * D_SZ;
    bf16x8 qf[4];
#pragma unroll
    for (int kc = 0; kc < 4; ++kc) {
        const float4 a = *reinterpret_cast<const float4*>(Q + qoff + kc * 32 + lg * 8);
        const float4 c = *reinterpret_cast<const float4*>(Q + qoff + kc * 32 + lg * 8 + 4);
        u16x8 u;
        u[0] = f2bf(a.x * SCALE_F); u[1] = f2bf(a.y * SCALE_F);
        u[2] = f2bf(a.z * SCALE_F); u[3] = f2bf(a.w * SCALE_F);
        u[4] = f2bf(c.x * SCALE_F); u[5] = f2bf(c.y * SCALE_F);
        u[6] = f2bf(c.z * SCALE_F); u[7] = f2bf(c.w * SCALE_F);
        qf[kc] = __builtin_bit_cast(bf16x8, u);
    }

    float m_r[4], l_r[4];
    f32x4 oacc[8];
#pragma unroll
    for (int r = 0; r < 4; ++r) { m_r[r] = -1e30f; l_r[r] = 0.f; }
#pragma unroll
    for (int n = 0; n < 8; ++n) oacc[n] = (f32x4){0.f, 0.f, 0.f, 0.f};

    const unsigned short* KbB = Kb + (size_t)b * S_SZ * D_SZ;
    const unsigned short* VtB = Vt + (size_t)b * D_SZ * S_SZ;
    unsigned short* pw = &Pl[w][0];

    for (int t = 0; t < S_SZ / KBLK; ++t) {
        const int k0 = t * KBLK;
        __syncthreads();  // previous tile's reads done before overwrite
        // ---- stage K tile [64][128] bf16 (16 KB), swizzled ----
#pragma unroll
        for (int j = 0; j < 4; ++j) {
            int c = tid + j * 256;
            int row = c >> 4, ch = c & 15;
            u32x4 v = *reinterpret_cast<const u32x4*>(KbB + (size_t)(k0 + row) * D_SZ + ch * 8);
            int idx = (row * 256 + ((ch * 16) ^ ((row & 7) << 4))) >> 1;
            *reinterpret_cast<u32x4*>(&Kl[idx]) = v;
        }
        // ---- stage V tile [128][64] bf16 (16 KB, d-major), swizzled ----
#pragma unroll
        for (int j = 0; j < 4; ++j) {
            int c = tid + j * 256;
            int dr = c >> 3, ch = c & 7;
            u32x4 v = *reinterpret_cast<const u32x4*>(VtB + (size_t)dr * S_SZ + k0 + ch * 8);
            int idx = (dr * 128 + ((ch * 16) ^ ((dr & 7) << 4))) >> 1;
            *reinterpret_cast<u32x4*>(&Vl[idx]) = v;
        }
        __syncthreads();

        // ---- QK^T: S[16q][64k], 16 MFMA ----
        f32x4 sacc[4];
#pragma unroll
        for (int n = 0; n < 4; ++n) sacc[n] = (f32x4){0.f, 0.f, 0.f, 0.f};
#pragma unroll
        for (int kc = 0; kc < 4; ++kc) {
#pragma unroll
            for (int n = 0; n < 4; ++n) {
                int key = n * 16 + l15;
                int idx = (key * 256 + ((kc * 64 + lg * 16) ^ ((key & 7) << 4))) >> 1;
                bf16x8 kf = *reinterpret_cast<const bf16x8*>(&Kl[idx]);
                sacc[n] = __builtin_amdgcn_mfma_f32_16x16x32_bf16(qf[kc], kf, sacc[n], 0, 0, 0);
            }
        }

        // ---- online softmax (rows lg*4+r; reduce over 16-lane column group) ----
#pragma unroll
        for (int r = 0; r < 4; ++r) {
            float mx = fmaxf(fmaxf(sacc[0][r], sacc[1][r]), fmaxf(sacc[2][r], sacc[3][r]));
            mx = fmaxf(mx, __shfl_xor(mx, 1));
            mx = fmaxf(mx, __shfl_xor(mx, 2));
            mx = fmaxf(mx, __shfl_xor(mx, 4));
            mx = fmaxf(mx, __shfl_xor(mx, 8));
            const float mnew = fmaxf(m_r[r], mx);
            const float corr = exp2f((m_r[r] - mnew) * LOG2E);
            const int row = lg * 4 + r;
            float rs = 0.f;
#pragma unroll
            for (int n = 0; n < 4; ++n) {
                float p = exp2f((sacc[n][r] - mnew) * LOG2E);
                rs += p;
                int idx = (row * 128 + (((n * 16 + l15) * 2) ^ ((row & 7) << 4))) >> 1;
                pw[idx] = f2bf(p);
            }
            rs += __shfl_xor(rs, 1);
            rs += __shfl_xor(rs, 2);
            rs += __shfl_xor(rs, 4);
            rs += __shfl_xor(rs, 8);
            l_r[r] = l_r[r] * corr + rs;
            m_r[r] = mnew;
#pragma unroll
            for (int n = 0; n < 8; ++n) oacc[n][r] *= corr;
        }
        asm volatile("s_waitcnt lgkmcnt(0)" ::: "memory");  // P writes visible (same wave)

        // ---- PV: O += P[16x64] * V[64x128], 16 MFMA ----
#pragma unroll
        for (int kc = 0; kc < 2; ++kc) {
            int pidx = (l15 * 128 + ((kc * 64 + lg * 16) ^ ((l15 & 7) << 4))) >> 1;
            bf16x8 pf = *reinterpret_cast<const bf16x8*>(&pw[pidx]);
#pragma unroll
            for (int nt = 0; nt < 8; ++nt) {
                int d = nt * 16 + l15;
                int vidx = (d * 128 + (((kc * 32 + lg * 8) * 2) ^ ((d & 7) << 4))) >> 1;
                bf16x8 vf = *reinterpret_cast<const bf16x8*>(&Vl[vidx]);
                oacc[nt] = __builtin_amdgcn_mfma_f32_16x16x32_bf16(pf, vf, oacc[nt], 0, 0, 0);
            }
        }
    }

    // ---- epilogue: O / l, fp32 out ----
    float* obase = Out + (((size_t)b * H_SZ + h) * S_SZ + qt * QBLK + w * 16) * D_SZ;
#pragma unroll
    for (int r = 0; r < 4; ++r) {
        const int row = lg * 4 + r;
        const float inv = 1.0f / l_r[r];
#pragma unroll
        for (int nt = 0; nt < 8; ++nt) {
            obase[(size_t)row * D_SZ + nt * 16 + l15] = oacc[nt][r] * inv;
        }
    }
}

extern "C" void kernel_launch(void* const* d_in, const int* in_sizes, int n_in,
                              void* d_out, int out_size, void* d_ws, size_t ws_size,
                              hipStream_t stream) {
    const float* Q = (const float*)d_in[0];
    const float* K = (const float*)d_in[1];
    const float* V = (const float*)d_in[2];
    float* Out = (float*)d_out;

    // workspace: Kb bf16 [B][S][D] (2 MB) then Vt bf16 [B][D][S] (2 MB)
    unsigned short* Kb = (unsigned short*)d_ws;
    unsigned short* Vt = Kb + (size_t)B_SZ * S_SZ * D_SZ;

    k_cvt_kernel<<<dim3((B_SZ * S_SZ * D_SZ / 4 + 255) / 256), dim3(256), 0, stream>>>(
        K, Kb, B_SZ * S_SZ * D_SZ / 4);
    v_tr_kernel<<<dim3(S_SZ / 64, D_SZ / 64, B_SZ), dim3(256), 0, stream>>>(V, Vt);
    mqa_fwd_kernel<<<dim3(S_SZ / QBLK, H_SZ, B_SZ), dim3(256), 0, stream>>>(Q, Kb, Vt, Out);
}

// Round 3
// 542.574 us; speedup vs baseline: 1.3368x; 1.3368x over previous
//
#include <hip/hip_runtime.h>

// MQA forward, MI355X gfx950. B=4 H=32 S=2048 D=128, fp32 I/O, bf16 MFMA.
// R3: bisection round. KEEP (new, formally verified): swapped QK^T so each
// lane holds one q-row -> in-register softmax (2+2 shuffles), log2-domain
// scores, defer-max THR=8. REVERT to R1-proven mechanics: register-staged
// K/V tiles (vector load + swizzled vector store), scalar f2bf P stores,
// libm exp2f. Added rule-#18 sched_barrier after the lgkmcnt wait.

#define B_SZ 4
#define H_SZ 32
#define S_SZ 2048
#define D_SZ 128
#define QBLK 64
#define KBLK 64
// (1/sqrt(128)) * log2(e): scores live in log2 domain
#define QSCALE 0.12751743f
#define DEFER_THR 8.0f

typedef __attribute__((ext_vector_type(8))) __bf16 bf16x8;
typedef __attribute__((ext_vector_type(8))) unsigned short u16x8;
typedef __attribute__((ext_vector_type(4))) float f32x4;
typedef __attribute__((ext_vector_type(4))) unsigned int u32x4;

static __device__ __forceinline__ unsigned short f2bf(float f) {
    unsigned int u = __builtin_bit_cast(unsigned int, f);
    u += 0x7fffu + ((u >> 16) & 1u);
    return (unsigned short)(u >> 16);
}

__global__ void k_cvt_kernel(const float* __restrict__ src,
                             unsigned short* __restrict__ dst, int n4) {
    int i = blockIdx.x * blockDim.x + threadIdx.x;
    if (i >= n4) return;
    float4 v = reinterpret_cast<const float4*>(src)[i];
    ushort4 o;
    o.x = f2bf(v.x); o.y = f2bf(v.y); o.z = f2bf(v.z); o.w = f2bf(v.w);
    reinterpret_cast<ushort4*>(dst)[i] = o;
}

__global__ void v_tr_kernel(const float* __restrict__ V,
                            unsigned short* __restrict__ Vt) {
    // 64x64 tile transpose through LDS. grid (S/64, D/64, B), 256 thr.
    __shared__ unsigned short T[64][72];
    const int k0 = blockIdx.x * 64;
    const int d0 = blockIdx.y * 64;
    const int b  = blockIdx.z;
    const int t  = threadIdx.x;
    const int r  = t >> 4;
    const int c4 = (t & 15) * 4;
#pragma unroll
    for (int rep = 0; rep < 4; ++rep) {
        int ki = rep * 16 + r;
        float4 v = *reinterpret_cast<const float4*>(
            &V[((size_t)(b * S_SZ + k0 + ki)) * D_SZ + d0 + c4]);
        T[ki][c4 + 0] = f2bf(v.x); T[ki][c4 + 1] = f2bf(v.y);
        T[ki][c4 + 2] = f2bf(v.z); T[ki][c4 + 3] = f2bf(v.w);
    }
    __syncthreads();
#pragma unroll
    for (int rep = 0; rep < 4; ++rep) {
        int di = rep * 16 + r;
        ushort4 o;
        o.x = T[c4 + 0][di]; o.y = T[c4 + 1][di];
        o.z = T[c4 + 2][di]; o.w = T[c4 + 3][di];
        *reinterpret_cast<ushort4*>(
            &Vt[((size_t)(b * D_SZ + d0 + di)) * S_SZ + k0 + c4]) = o;
    }
}

__global__ __launch_bounds__(256) void mqa_fwd_kernel(
        const float* __restrict__ Q,
        const unsigned short* __restrict__ Kb,   // [B][S][D] bf16
        const unsigned short* __restrict__ Vt,   // [B][D][S] bf16
        float* __restrict__ Out)
{
    __shared__ __align__(16) unsigned short Kl[64 * 128];   // [key][d], swizzled
    __shared__ __align__(16) unsigned short Vl[128 * 64];   // [d][key], swizzled
    __shared__ __align__(16) unsigned short Pl[4][16 * 64]; // per-wave [q][key], swizzled

    const int tid  = threadIdx.x;
    const int lane = tid & 63;
    const int w    = tid >> 6;
    const int l15  = lane & 15;
    const int lg   = lane >> 4;

    const int qt = blockIdx.x;
    const int h  = blockIdx.y;
    const int b  = blockIdx.z;

    // ---- Q fragments (used as MFMA B-operand: col=q=l15, k=lg*8+i), log2-scaled ----
    const size_t qoff = (((size_t)b * H_SZ + h) * S_SZ + qt * QBLK + w * 16 + l15) * D_SZ;
    bf16x8 qf[4];
#pragma unroll
    for (int kc = 0; kc < 4; ++kc) {
        const float4 a = *reinterpret_cast<const float4*>(Q + qoff + kc * 32 + lg * 8);
        const float4 c = *reinterpret_cast<const float4*>(Q + qoff + kc * 32 + lg * 8 + 4);
        u16x8 u;
        u[0] = f2bf(a.x * QSCALE); u[1] = f2bf(a.y * QSCALE);
        u[2] = f2bf(a.z * QSCALE); u[3] = f2bf(a.w * QSCALE);
        u[4] = f2bf(c.x * QSCALE); u[5] = f2bf(c.y * QSCALE);
        u[6] = f2bf(c.z * QSCALE); u[7] = f2bf(c.w * QSCALE);
        qf[kc] = __builtin_bit_cast(bf16x8, u);
    }

    float m_s = -1e30f, l_s = 0.f;
    f32x4 oacc[8];
#pragma unroll
    for (int n = 0; n < 8; ++n) oacc[n] = (f32x4){0.f, 0.f, 0.f, 0.f};

    const unsigned short* KbB = Kb + (size_t)b * S_SZ * D_SZ;
    const unsigned short* VtB = Vt + (size_t)b * D_SZ * S_SZ;
    unsigned short* pw = &Pl[w][0];

    for (int t = 0; t < S_SZ / KBLK; ++t) {
        const int k0 = t * KBLK;
        __syncthreads();  // previous tile's reads done before overwrite
        // ---- stage K tile [64][128] bf16, swizzled (R1-proven) ----
#pragma unroll
        for (int j = 0; j < 4; ++j) {
            int c = tid + j * 256;
            int row = c >> 4, ch = c & 15;
            u32x4 v = *reinterpret_cast<const u32x4*>(KbB + (size_t)(k0 + row) * D_SZ + ch * 8);
            int idx = (row * 256 + ((ch * 16) ^ ((row & 7) << 4))) >> 1;
            *reinterpret_cast<u32x4*>(&Kl[idx]) = v;
        }
        // ---- stage V tile [128][64] bf16 (d-major), swizzled (R1-proven) ----
#pragma unroll
        for (int j = 0; j < 4; ++j) {
            int c = tid + j * 256;
            int dr = c >> 3, ch = c & 7;
            u32x4 v = *reinterpret_cast<const u32x4*>(VtB + (size_t)dr * S_SZ + k0 + ch * 8);
            int idx = (dr * 128 + ((ch * 16) ^ ((dr & 7) << 4))) >> 1;
            *reinterpret_cast<u32x4*>(&Vl[idx]) = v;
        }
        __syncthreads();

        // ---- swapped QK^T: D[key][q], lane (l15,lg) holds q=l15, keys n*16+lg*4+r ----
        f32x4 sacc[4];
#pragma unroll
        for (int n = 0; n < 4; ++n) sacc[n] = (f32x4){0.f, 0.f, 0.f, 0.f};
#pragma unroll
        for (int kc = 0; kc < 4; ++kc) {
#pragma unroll
            for (int n = 0; n < 4; ++n) {
                int key = n * 16 + l15;
                int idx = (key * 256 + ((kc * 64 + lg * 16) ^ ((key & 7) << 4))) >> 1;
                bf16x8 kf = *reinterpret_cast<const bf16x8*>(&Kl[idx]);
                sacc[n] = __builtin_amdgcn_mfma_f32_16x16x32_bf16(kf, qf[kc], sacc[n], 0, 0, 0);
            }
        }

        // ---- online softmax, one q-row per lane (4 redundant copies), log2 domain ----
        float mx = sacc[0][0];
#pragma unroll
        for (int n = 0; n < 4; ++n) {
#pragma unroll
            for (int r = 0; r < 4; ++r) mx = fmaxf(mx, sacc[n][r]);
        }
        mx = fmaxf(mx, __shfl_xor(mx, 16));
        mx = fmaxf(mx, __shfl_xor(mx, 32));
        if (!__all(mx <= m_s + DEFER_THR)) {
            const float mnew = fmaxf(m_s, mx);
            const float corr = exp2f(m_s - mnew);
            l_s *= corr;
            m_s = mnew;
            // O rows are q = lg*4+r; softmax state lives at lane l15=q
            const float c0 = __shfl(corr, lg * 4 + 0);
            const float c1 = __shfl(corr, lg * 4 + 1);
            const float c2 = __shfl(corr, lg * 4 + 2);
            const float c3 = __shfl(corr, lg * 4 + 3);
#pragma unroll
            for (int nt = 0; nt < 8; ++nt) {
                oacc[nt][0] *= c0; oacc[nt][1] *= c1;
                oacc[nt][2] *= c2; oacc[nt][3] *= c3;
            }
        }
        float rs = 0.f;
#pragma unroll
        for (int n = 0; n < 4; ++n) {
#pragma unroll
            for (int r = 0; r < 4; ++r) {
                const float p = exp2f(sacc[n][r] - m_s);
                rs += p;
                const int key = n * 16 + lg * 4 + r;
                int idx = (l15 * 128 + ((key * 2) ^ ((l15 & 7) << 4))) >> 1;
                pw[idx] = f2bf(p);
            }
        }
        rs += __shfl_xor(rs, 16);
        rs += __shfl_xor(rs, 32);
        l_s += rs;
        asm volatile("s_waitcnt lgkmcnt(0)" ::: "memory");  // P writes visible
        __builtin_amdgcn_sched_barrier(0);                   // rule #18 fence

        // ---- PV: O[16q][128d] += P[16q][64k] * V (R1-proven reads) ----
#pragma unroll
        for (int kc = 0; kc < 2; ++kc) {
            int pidx = (l15 * 128 + ((kc * 64 + lg * 16) ^ ((l15 & 7) << 4))) >> 1;
            bf16x8 pf = *reinterpret_cast<const bf16x8*>(&pw[pidx]);
#pragma unroll
            for (int nt = 0; nt < 8; ++nt) {
                int d = nt * 16 + l15;
                int vidx = (d * 128 + (((kc * 32 + lg * 8) * 2) ^ ((d & 7) << 4))) >> 1;
                bf16x8 vf = *reinterpret_cast<const bf16x8*>(&Vl[vidx]);
                oacc[nt] = __builtin_amdgcn_mfma_f32_16x16x32_bf16(pf, vf, oacc[nt], 0, 0, 0);
            }
        }
    }

    // ---- epilogue: O / l (l broadcast from state lane l15 = q-row) ----
    float linv[4];
#pragma unroll
    for (int r = 0; r < 4; ++r) linv[r] = 1.0f / __shfl(l_s, lg * 4 + r);
    float* obase = Out + (((size_t)b * H_SZ + h) * S_SZ + qt * QBLK + w * 16) * D_SZ;
#pragma unroll
    for (int r = 0; r < 4; ++r) {
        const int row = lg * 4 + r;
#pragma unroll
        for (int nt = 0; nt < 8; ++nt) {
            obase[(size_t)row * D_SZ + nt * 16 + l15] = oacc[nt][r] * linv[r];
        }
    }
}

extern "C" void kernel_launch(void* const* d_in, const int* in_sizes, int n_in,
                              void* d_out, int out_size, void* d_ws, size_t ws_size,
                              hipStream_t stream) {
    const float* Q = (const float*)d_in[0];
    const float* K = (const float*)d_in[1];
    const float* V = (const float*)d_in[2];
    float* Out = (float*)d_out;

    unsigned short* Kb = (unsigned short*)d_ws;
    unsigned short* Vt = Kb + (size_t)B_SZ * S_SZ * D_SZ;

    k_cvt_kernel<<<dim3((B_SZ * S_SZ * D_SZ / 4 + 255) / 256), dim3(256), 0, stream>>>(
        K, Kb, B_SZ * S_SZ * D_SZ / 4);
    v_tr_kernel<<<dim3(S_SZ / 64, D_SZ / 64, B_SZ), dim3(256), 0, stream>>>(V, Vt);
    mqa_fwd_kernel<<<dim3(S_SZ / QBLK, H_SZ, B_SZ), dim3(256), 0, stream>>>(Q, Kb, Vt, Out);
}